// Round 8
// baseline (332.008 us; speedup 1.0000x reference)
//
#include <hip/hip_runtime.h>

typedef unsigned short u16;
typedef unsigned int u32;
typedef __attribute__((ext_vector_type(8))) short bf16x8;
typedef __attribute__((ext_vector_type(4))) float f32x4;

// round-to-nearest-even f32 -> bf16
__device__ inline u16 f2bf(float x) {
  union { float f; unsigned u; } v; v.f = x;
  unsigned r = v.u + 0x7fffu + ((v.u >> 16) & 1u);
  return (u16)(r >> 16);
}

// pack two f32 -> two bf16 (truncation) in ONE v_perm_b32. bytes: [p1.hi16, p0.hi16]
__device__ inline u32 packbf2(float p0, float p1) {
  return __builtin_amdgcn_perm(__float_as_uint(p1), __float_as_uint(p0), 0x07060302u);
}

// async global->LDS, 16B per lane. lds dst = wave-uniform base + lane*16.
__device__ inline void gload16(const void* g, void* l) {
  __builtin_amdgcn_global_load_lds(
      (const __attribute__((address_space(1))) unsigned int*)g,
      (__attribute__((address_space(3))) unsigned int*)l,
      16, 0, 0);
}

// one fused f32->bf16 conversion for ALL 7 tensors.
__global__ void cvt_all(const float* __restrict__ q, const float* __restrict__ k,
                        const float* __restrict__ v,
                        const float* __restrict__ wq, const float* __restrict__ wk,
                        const float* __restrict__ wv, const float* __restrict__ wo,
                        u16* __restrict__ ws) {
  const size_t MT4 = (size_t)2 * 1024 * 1024;   // 8M elems / 4
  const int i = blockIdx.x * blockDim.x + threadIdx.x;
  const int t = blockIdx.y;
  float4 vv;
  ushort4 o;
  if (t < 3) {
    const float* src = (t == 0) ? q : (t == 1) ? k : v;
    vv = ((const float4*)src)[i];
    o.x = f2bf(vv.x); o.y = f2bf(vv.y); o.z = f2bf(vv.z); o.w = f2bf(vv.w);
    ((ushort4*)ws)[(size_t)t * MT4 + i] = o;
  } else {
    if (i >= (1 << 20)) return;                 // 4 * 256K float4
    const int w = i >> 18, j = i & 0x3FFFF;
    const float* src = (w == 0) ? wq : (w == 1) ? wk : (w == 2) ? wv : wo;
    vv = ((const float4*)src)[j];
    o.x = f2bf(vv.x); o.y = f2bf(vv.y); o.z = f2bf(vv.z); o.w = f2bf(vv.w);
    ((ushort4*)(ws + 3 * MT4 * 4))[i] = o;
  }
}

// ---------------- fused Q/K/V projection GEMM (unchanged) ------
// 3-buffer LDS pipeline, prefetch distance 2, counted vmcnt(4) + raw barrier.
__global__ __launch_bounds__(256, 3) void gemm_qkv(
    const u16* __restrict__ Xq, const u16* __restrict__ Wqb,
    const float* __restrict__ bq_, const float* __restrict__ bk_,
    const float* __restrict__ bv_, u16* __restrict__ Qp)
{
  constexpr int N = 1024, K = 1024, BK = 32, NT = K / BK;
  constexpr size_t MT = (size_t)8192 * 1024, WT = (size_t)1024 * 1024;
  __shared__ __align__(16) u16 As[3][128 * BK];   // 24 KB
  __shared__ __align__(16) u16 Bs[3][128 * BK];   // 24 KB (total 48 KB)
  const int z = blockIdx.z;
  const u16* A = Xq + (size_t)z * MT;
  const u16* W = Wqb + (size_t)z * WT;
  const float* bias = (z == 0) ? bq_ : (z == 1) ? bk_ : bv_;
  u16* Cout = Qp + (size_t)z * MT;
  const bool vm = (z == 2);

  const int tid = threadIdx.x;
  const int wave = tid >> 6, lane = tid & 63;
  const int quad = lane >> 4, l16 = lane & 15;
  const int m0 = blockIdx.x * 128, n0 = blockIdx.y * 128;

  const int sA = wave * 2;
  const int srow = lane >> 2;
  const int skcol = ((lane & 3) ^ (srow & 3)) * 8;   // source granule pre-swizzle
  const int mloc = sA * 16 + srow;
  const int arow = vm ? ((mloc & 64) + (mloc & 3) * 16 + ((mloc & 63) >> 2)) : mloc;
  const int astep = vm ? 4 : 16;
  const u16* ag = A + (size_t)(m0 + arow) * K + skcol;
  const u16* bg = W + (size_t)(n0 + mloc) * K + skcol;

  const int wm = (wave >> 1) * 64, wn = (wave & 1) * 64;
  f32x4 acc[4][4] = {};

#define QKV_STAGE(s)                                   \
  do {                                                 \
    gload16(ag, As[s] + sA * 512);                     \
    gload16(ag + (size_t)astep * K, As[s] + sA * 512 + 512); \
    gload16(bg, Bs[s] + sA * 512);                     \
    gload16(bg + 16 * K, Bs[s] + sA * 512 + 512);      \
    ag += BK; bg += BK;                                \
  } while (0)

  QKV_STAGE(0);
  QKV_STAGE(1);

  int cb = 0, sb = 2;   // compute-buffer, stage-buffer (cycle mod 3)
  for (int kt = 0; kt < NT; ++kt) {
    if (kt + 1 < NT) asm volatile("s_waitcnt vmcnt(4)" ::: "memory");
    else             asm volatile("s_waitcnt vmcnt(0)" ::: "memory");
    __builtin_amdgcn_s_barrier();
    __builtin_amdgcn_sched_barrier(0);
    if (kt + 2 < NT) {
      QKV_STAGE(sb);
      sb = (sb == 2) ? 0 : sb + 1;
    }
    const u16* Ac = As[cb];
    const u16* Bc = Bs[cb];
    cb = (cb == 2) ? 0 : cb + 1;
    bf16x8 af[4], bf[4];
#pragma unroll
    for (int mi = 0; mi < 4; ++mi)
      af[mi] = *(const bf16x8*)(Ac + (wm + mi * 16 + l16) * BK + ((quad ^ (l16 & 3)) * 8));
#pragma unroll
    for (int ni = 0; ni < 4; ++ni)
      bf[ni] = *(const bf16x8*)(Bc + (wn + ni * 16 + l16) * BK + ((quad ^ (l16 & 3)) * 8));
#pragma unroll
    for (int mi = 0; mi < 4; ++mi)
#pragma unroll
      for (int ni = 0; ni < 4; ++ni)
        acc[mi][ni] = __builtin_amdgcn_mfma_f32_16x16x32_bf16(af[mi], bf[ni], acc[mi][ni], 0, 0, 0);
  }
#undef QKV_STAGE

#pragma unroll
  for (int ni = 0; ni < 4; ++ni) {
    const int col = n0 + wn + ni * 16 + l16;
    const float bv = bias[col];
#pragma unroll
    for (int mi = 0; mi < 4; ++mi) {
      const int mrow = m0 + wm + mi * 16 + quad * 4;
      f32x4 a = acc[mi][ni];
      if (!vm) {
#pragma unroll
        for (int r = 0; r < 4; ++r)
          Cout[(size_t)(mrow + r) * N + col] = f2bf(a[r] + bv);
      } else {
        const int bq = mrow >> 11, t = mrow & 2047;
        const int h = col >> 6, d = col & 63;
        ushort4 pk;
        pk.x = f2bf(a[0] + bv); pk.y = f2bf(a[1] + bv);
        pk.z = f2bf(a[2] + bv); pk.w = f2bf(a[3] + bv);
        *(ushort4*)(Cout + ((size_t)((bq * 16 + h) * 64 + d)) * 2048 + t) = pk;
      }
    }
  }
}

// ---------------- Wo GEMM (fp32 out) — round-5 version (measured best) ------
// 128x128 tile, (256,2), 3-buffer dist-2 counted vmcnt(4). The 128x64/(256,4)
// re-tile of round 7 measured -3 us total vs this: reverted.
__global__ __launch_bounds__(256, 2) void gemm_wo(
    const u16* __restrict__ A, const u16* __restrict__ W,
    const float* __restrict__ bias, float* __restrict__ Cout)
{
  constexpr int N = 1024, K = 1024, BK = 32, NT = K / BK;
  __shared__ __align__(16) u16 As[3][128 * BK];
  __shared__ __align__(16) u16 Bs[3][128 * BK];
  const int tid = threadIdx.x;
  const int wave = tid >> 6, lane = tid & 63;
  const int quad = lane >> 4, l16 = lane & 15;
  const int m0 = blockIdx.x * 128, n0 = blockIdx.y * 128;

  const int sA = wave * 2;
  const int srow = lane >> 2;
  const int skcol = ((lane & 3) ^ (srow & 3)) * 8;
  const int mloc = sA * 16 + srow;
  const u16* ag = A + (size_t)(m0 + mloc) * K + skcol;
  const u16* bg = W + (size_t)(n0 + mloc) * K + skcol;

  const int wm = (wave >> 1) * 64, wn = (wave & 1) * 64;
  f32x4 acc[4][4] = {};

#define WO_STAGE(s)                                    \
  do {                                                 \
    gload16(ag, As[s] + sA * 512);                     \
    gload16(ag + 16 * K, As[s] + sA * 512 + 512);      \
    gload16(bg, Bs[s] + sA * 512);                     \
    gload16(bg + 16 * K, Bs[s] + sA * 512 + 512);      \
    ag += BK; bg += BK;                                \
  } while (0)

  WO_STAGE(0);
  WO_STAGE(1);

  int cb = 0, sb = 2;
  for (int kt = 0; kt < NT; ++kt) {
    if (kt + 1 < NT) asm volatile("s_waitcnt vmcnt(4)" ::: "memory");
    else             asm volatile("s_waitcnt vmcnt(0)" ::: "memory");
    __builtin_amdgcn_s_barrier();
    __builtin_amdgcn_sched_barrier(0);
    if (kt + 2 < NT) {
      WO_STAGE(sb);
      sb = (sb == 2) ? 0 : sb + 1;
    }
    const u16* Ac = As[cb];
    const u16* Bc = Bs[cb];
    cb = (cb == 2) ? 0 : cb + 1;
    bf16x8 af[4], bf[4];
#pragma unroll
    for (int mi = 0; mi < 4; ++mi)
      af[mi] = *(const bf16x8*)(Ac + (wm + mi * 16 + l16) * BK + ((quad ^ (l16 & 3)) * 8));
#pragma unroll
    for (int ni = 0; ni < 4; ++ni)
      bf[ni] = *(const bf16x8*)(Bc + (wn + ni * 16 + l16) * BK + ((quad ^ (l16 & 3)) * 8));
#pragma unroll
    for (int mi = 0; mi < 4; ++mi)
#pragma unroll
      for (int ni = 0; ni < 4; ++ni)
        acc[mi][ni] = __builtin_amdgcn_mfma_f32_16x16x32_bf16(af[mi], bf[ni], acc[mi][ni], 0, 0, 0);
  }
#undef WO_STAGE

#pragma unroll
  for (int ni = 0; ni < 4; ++ni) {
    const int col = n0 + wn + ni * 16 + l16;
    const float bv = bias[col];
#pragma unroll
    for (int mi = 0; mi < 4; ++mi) {
      const int mrow = m0 + wm + mi * 16 + quad * 4;
      f32x4 a = acc[mi][ni];
#pragma unroll
      for (int r = 0; r < 4; ++r)
        Cout[(size_t)(mrow + r) * N + col] = a[r] + bv;
    }
  }
}

// ---------------- flash attention ----------------
// Round-8 change: KVBLK 128 -> 64. LDS 81920 -> 49152 B (K dbuf 16K + V dbuf
// 16K + P 16K) -> 3 blocks/CU = 6 waves/SIMD (was 2/CU = 4). Round-7 counters:
// MfmaUtil 41 + VALUBusy 49 = 92% summed with ~40% idle issue slots -> barrier-
// lockstep serializes the pipes; more resident waves fill the stall cycles.
// Per-kt body = exactly the old per-g half (same live regs -> VGPR stays ~64,
// no spill). 32 kt x 1 barrier. V rows now 8 granules: write g^(d&7), read
// (ksl*4+quad)^(l16&7) (<=2-way, free). Permutation is per-64-half, so Vt
// layout and P mapping are unchanged.
__global__ __launch_bounds__(512, 4) void flash_attn(
    const u16* __restrict__ Qp, const u16* __restrict__ Kp,
    const u16* __restrict__ Vt, u16* __restrict__ Ctx)
{
  constexpr int TQ = 2048, DM = 1024, DK = 64;
  __shared__ __align__(16) u16 Ks[2][64 * 64];     // 16384 B
  __shared__ __align__(16) u16 Vts[2][64 * 64];    // 16384 B
  __shared__ __align__(16) u16 Ps[8][16 * 64];     // 16384 B  (total 49152)

  const int bh = blockIdx.x, b = bh >> 4, h = bh & 15;
  const int qt = blockIdx.y;
  const int tid = threadIdx.x, wave = tid >> 6, lane = tid & 63;
  const int quad = lane >> 4, l16 = lane & 15;
  const int q0 = qt * 256 + wave * 32;

  // staging: 512 threads x 16B = one 64x64 tile per round. K: row=tid>>3,
  // granule=(tid&7)^(row&7). V: d=tid>>3, granule=(tid&7)^(d&7).
  const int kr = tid >> 3;
  const u16* kp = Kp + (size_t)(b * TQ + kr) * DM + h * DK + (((tid & 7) ^ (kr & 7)) * 8);
  const int vd = tid >> 3;
  const u16* vp = Vt + (size_t)(bh * DK + vd) * TQ + (((tid & 7) ^ (vd & 7)) * 8);

  bf16x8 qf[2][2];
#pragma unroll
  for (int mi = 0; mi < 2; ++mi)
#pragma unroll
    for (int ks = 0; ks < 2; ++ks)
      qf[mi][ks] = *(const bf16x8*)(Qp + (size_t)(b * TQ + q0 + mi * 16 + l16) * DM
                                       + h * DK + ks * 32 + quad * 8);

  f32x4 O[2][4] = {};
  f32x4 lsum[2] = {};
  const float CS = 0.18033688011112042f;
  const float CB = 0.0028153f;

  bf16x8 onesv;
#pragma unroll
  for (int j = 0; j < 8; ++j) onesv[j] = (short)0x3F80;  // bf16 1.0

  gload16(kp, &Ks[0][tid * 8]);
  gload16(vp, &Vts[0][tid * 8]);
  kp += 64 * DM; vp += 64;
  __syncthreads();

  const int kg = quad ^ (l16 & 7);
  int cur = 0;
  for (int kt = 0; kt < TQ / 64; ++kt) {
    if (kt + 1 < TQ / 64) {
      const int nb = cur ^ 1;
      gload16(kp, &Ks[nb][tid * 8]);
      gload16(vp, &Vts[nb][tid * 8]);
      kp += 64 * DM; vp += 64;
    }
    const u16* Kc = Ks[cur];
    const u16* Vc = Vts[cur];
    u16* Psw = Ps[wave];

    f32x4 Sg[2][4];
    __builtin_amdgcn_s_setprio(1);
#pragma unroll
    for (int cc = 0; cc < 4; ++cc) {
      const int row = cc * 16 + l16;
      bf16x8 kf0 = *(const bf16x8*)(Kc + row * 64 + kg * 8);
      bf16x8 kf1 = *(const bf16x8*)(Kc + row * 64 + (kg ^ 4) * 8);
#pragma unroll
      for (int mi = 0; mi < 2; ++mi) {
        f32x4 zz = {};
        zz = __builtin_amdgcn_mfma_f32_16x16x32_bf16(qf[mi][0], kf0, zz, 0, 0, 0);
        Sg[mi][cc] = __builtin_amdgcn_mfma_f32_16x16x32_bf16(qf[mi][1], kf1, zz, 0, 0, 0);
      }
    }
    __builtin_amdgcn_s_setprio(0);
    bf16x8 pf[2][2];
#pragma unroll
    for (int mi = 0; mi < 2; ++mi) {
      // exp2 -> bf16 pack -> P(LDS). col l16*4+cc holds key cc*16+l16.
#pragma unroll
      for (int r = 0; r < 4; ++r) {
        float e0 = __builtin_amdgcn_exp2f(fmaf(Sg[mi][0][r], CS, CB));
        float e1 = __builtin_amdgcn_exp2f(fmaf(Sg[mi][1][r], CS, CB));
        float e2 = __builtin_amdgcn_exp2f(fmaf(Sg[mi][2][r], CS, CB));
        float e3 = __builtin_amdgcn_exp2f(fmaf(Sg[mi][3][r], CS, CB));
        uint2 pk;
        pk.x = packbf2(e0, e1);
        pk.y = packbf2(e2, e3);
        const int pw = quad * 4 + r;
        *(uint2*)(&Psw[pw * 64 + ((l16 * 4) ^ ((pw & 7) << 3))]) = pk;
      }
      // read back in A-layout (row = l16); same-wave DS ops are in-order
#pragma unroll
      for (int ksl = 0; ksl < 2; ++ksl)
        pf[mi][ksl] = *(const bf16x8*)(&Psw[l16 * 64 + ((ksl * 32 + quad * 8) ^ ((l16 & 7) << 3))]);
#pragma unroll
      for (int ksl = 0; ksl < 2; ++ksl)
        lsum[mi] = __builtin_amdgcn_mfma_f32_16x16x32_bf16(pf[mi][ksl], onesv, lsum[mi], 0, 0, 0);
    }
    __builtin_amdgcn_s_setprio(1);
#pragma unroll
    for (int ksl = 0; ksl < 2; ++ksl)
#pragma unroll
      for (int ni = 0; ni < 4; ++ni) {
        const int gv = ksl * 4 + quad;
        bf16x8 vf = *(const bf16x8*)(Vc + (ni * 16 + l16) * 64 + ((gv ^ (l16 & 7)) * 8));
        O[0][ni] = __builtin_amdgcn_mfma_f32_16x16x32_bf16(pf[0][ksl], vf, O[0][ni], 0, 0, 0);
        O[1][ni] = __builtin_amdgcn_mfma_f32_16x16x32_bf16(pf[1][ksl], vf, O[1][ni], 0, 0, 0);
      }
    __builtin_amdgcn_s_setprio(0);

    __syncthreads();
    cur ^= 1;
  }

  // epilogue: O /= l, write context [B,T,D] bf16
#pragma unroll
  for (int mi = 0; mi < 2; ++mi)
#pragma unroll
    for (int r = 0; r < 4; ++r) {
      const float inv = 1.0f / lsum[mi][r];
      const int q = q0 + mi * 16 + quad * 4 + r;
#pragma unroll
      for (int ni = 0; ni < 4; ++ni) {
        const int col = h * DK + ni * 16 + l16;
        Ctx[(size_t)(b * TQ + q) * DM + col] = f2bf(O[mi][ni][r] * inv);
      }
    }
}

extern "C" void kernel_launch(void* const* d_in, const int* in_sizes, int n_in,
                              void* d_out, int out_size, void* d_ws, size_t ws_size,
                              hipStream_t stream)
{
  (void)in_sizes; (void)n_in; (void)out_size; (void)ws_size;
  const float* query = (const float*)d_in[0];
  const float* key_  = (const float*)d_in[1];
  const float* value = (const float*)d_in[2];
  const float* Wq = (const float*)d_in[3];
  const float* bq = (const float*)d_in[4];
  const float* Wk = (const float*)d_in[5];
  const float* bk = (const float*)d_in[6];
  const float* Wv = (const float*)d_in[7];
  const float* bv = (const float*)d_in[8];
  const float* Wo = (const float*)d_in[9];
  const float* bo = (const float*)d_in[10];

  const size_t MT = (size_t)4 * 2048 * 1024;  // 8M elements
  const size_t WT = (size_t)1024 * 1024;      // 1M elements
  u16* ws  = (u16*)d_ws;
  u16* Xq  = ws;                 // Xq, Xk, Xv contiguous (stride MT)
  u16* Wqb = Xq + 3 * MT;        // Wqb, Wkb, Wvb, Wob contiguous (stride WT)
  u16* Qp  = Wqb + 4 * WT;       // Qp, Kp, Vt contiguous (stride MT)
  u16* Kp  = Qp + MT;
  u16* Vt  = Kp + MT;
  u16* Ctx = Vt + MT;
  u16* Wob = Wqb + 3 * WT;

  cvt_all<<<dim3(8192, 4), 256, 0, stream>>>(
      query, key_, value, Wq, Wk, Wv, Wo, ws);

  gemm_qkv<<<dim3(64, 8, 3), 256, 0, stream>>>(Xq, Wqb, bq, bk, bv, Qp);

  flash_attn<<<dim3(64, 8), 512, 0, stream>>>(Qp, Kp, Vt, Ctx);

  gemm_wo<<<dim3(64, 8), 256, 0, stream>>>(Ctx, Wob, bo, (float*)d_out);
}

// Round 9
// 325.013 us; speedup vs baseline: 1.0215x; 1.0215x over previous
//
#include <hip/hip_runtime.h>

typedef unsigned short u16;
typedef unsigned int u32;
typedef __attribute__((ext_vector_type(8))) short bf16x8;
typedef __attribute__((ext_vector_type(4))) float f32x4;

// round-to-nearest-even f32 -> bf16
__device__ inline u16 f2bf(float x) {
  union { float f; unsigned u; } v; v.f = x;
  unsigned r = v.u + 0x7fffu + ((v.u >> 16) & 1u);
  return (u16)(r >> 16);
}

// pack two f32 -> two bf16 (truncation) in ONE v_perm_b32. bytes: [p1.hi16, p0.hi16]
__device__ inline u32 packbf2(float p0, float p1) {
  return __builtin_amdgcn_perm(__float_as_uint(p1), __float_as_uint(p0), 0x07060302u);
}

// async global->LDS, 16B per lane. lds dst = wave-uniform base + lane*16.
__device__ inline void gload16(const void* g, void* l) {
  __builtin_amdgcn_global_load_lds(
      (const __attribute__((address_space(1))) unsigned int*)g,
      (__attribute__((address_space(3))) unsigned int*)l,
      16, 0, 0);
}

// one fused f32->bf16 conversion for ALL 7 tensors.
__global__ void cvt_all(const float* __restrict__ q, const float* __restrict__ k,
                        const float* __restrict__ v,
                        const float* __restrict__ wq, const float* __restrict__ wk,
                        const float* __restrict__ wv, const float* __restrict__ wo,
                        u16* __restrict__ ws) {
  const size_t MT4 = (size_t)2 * 1024 * 1024;   // 8M elems / 4
  const int i = blockIdx.x * blockDim.x + threadIdx.x;
  const int t = blockIdx.y;
  float4 vv;
  ushort4 o;
  if (t < 3) {
    const float* src = (t == 0) ? q : (t == 1) ? k : v;
    vv = ((const float4*)src)[i];
    o.x = f2bf(vv.x); o.y = f2bf(vv.y); o.z = f2bf(vv.z); o.w = f2bf(vv.w);
    ((ushort4*)ws)[(size_t)t * MT4 + i] = o;
  } else {
    if (i >= (1 << 20)) return;                 // 4 * 256K float4
    const int w = i >> 18, j = i & 0x3FFFF;
    const float* src = (w == 0) ? wq : (w == 1) ? wk : (w == 2) ? wv : wo;
    vv = ((const float4*)src)[j];
    o.x = f2bf(vv.x); o.y = f2bf(vv.y); o.z = f2bf(vv.z); o.w = f2bf(vv.w);
    ((ushort4*)(ws + 3 * MT4 * 4))[i] = o;
  }
}

// ---------------- fused Q/K/V projection GEMM ----------------
// Round-9 change: 512-thread blocks (8 waves x 64x32 subtiles). Round-8
// analysis: qkv occupancy was THREAD-capped (256-thr blocks: 3 blocks x 4
// waves = 12 waves/CU) while grid (6/CU), LDS (3/CU), VGPR (9 w/SIMD) all
// allowed more. 8-wave blocks: 3 blocks x 8 = 24 waves/CU if VGPR <= 85
// (liveness est ~75). launch_bounds (512,4) = 128-reg budget: NO spill risk
// (R1/R6 lesson); actual occupancy follows actual VGPR.
// Pipeline unchanged: 3-buffer LDS, prefetch dist 2, counted vmcnt + barrier.
// Staging: 1 A-load + 1 B-load per thread (row tid>>2, granule (tid&3)^(row&3)
// pre-swizzled at the source; LDS dest linear) -> vmcnt(2) in steady state.
// z<2: bf16 out [M,N]. z==2: Vt layout, key-permuted per 64-half:
//   Vt[((b*16+h)*64+d)*2048 + a], tok(a) = (a&~127)+(a&64)+(a&3)*16+((a&63)>>2).
__global__ __launch_bounds__(512, 4) void gemm_qkv(
    const u16* __restrict__ Xq, const u16* __restrict__ Wqb,
    const float* __restrict__ bq_, const float* __restrict__ bk_,
    const float* __restrict__ bv_, u16* __restrict__ Qp)
{
  constexpr int N = 1024, K = 1024, BK = 32, NT = K / BK;
  constexpr size_t MT = (size_t)8192 * 1024, WT = (size_t)1024 * 1024;
  __shared__ __align__(16) u16 As[3][128 * BK];   // 24 KB
  __shared__ __align__(16) u16 Bs[3][128 * BK];   // 24 KB (total 48 KB)
  const int z = blockIdx.z;
  const u16* A = Xq + (size_t)z * MT;
  const u16* W = Wqb + (size_t)z * WT;
  const float* bias = (z == 0) ? bq_ : (z == 1) ? bk_ : bv_;
  u16* Cout = Qp + (size_t)z * MT;
  const bool vm = (z == 2);

  const int tid = threadIdx.x;
  const int wave = tid >> 6, lane = tid & 63;
  const int quad = lane >> 4, l16 = lane & 15;
  const int m0 = blockIdx.x * 128, n0 = blockIdx.y * 128;

  // staging: thread t loads row t>>2, source granule (t&3)^(row&3) (16B units)
  const int srow = tid >> 2;
  const int sg = ((tid & 3) ^ (srow & 3)) * 8;
  const int arowP = vm ? ((srow & 64) + (srow & 3) * 16 + ((srow & 63) >> 2)) : srow;
  const u16* ag = A + (size_t)(m0 + arowP) * K + sg;
  const u16* bg = W + (size_t)(n0 + srow) * K + sg;

  const int wm = (wave >> 2) * 64, wn = (wave & 3) * 32;
  f32x4 acc[4][2] = {};

#define QKV_STAGE(s)                                   \
  do {                                                 \
    gload16(ag, As[s] + wave * 512);                   \
    gload16(bg, Bs[s] + wave * 512);                   \
    ag += BK; bg += BK;                                \
  } while (0)

  QKV_STAGE(0);
  QKV_STAGE(1);

  int cb = 0, sb = 2;   // compute-buffer, stage-buffer (cycle mod 3)
  for (int kt = 0; kt < NT; ++kt) {
    if (kt + 1 < NT) asm volatile("s_waitcnt vmcnt(2)" ::: "memory");
    else             asm volatile("s_waitcnt vmcnt(0)" ::: "memory");
    __builtin_amdgcn_s_barrier();
    __builtin_amdgcn_sched_barrier(0);
    if (kt + 2 < NT) {
      QKV_STAGE(sb);
      sb = (sb == 2) ? 0 : sb + 1;
    }
    const u16* Ac = As[cb];
    const u16* Bc = Bs[cb];
    cb = (cb == 2) ? 0 : cb + 1;
    bf16x8 af[4], bf[2];
#pragma unroll
    for (int mi = 0; mi < 4; ++mi)
      af[mi] = *(const bf16x8*)(Ac + (wm + mi * 16 + l16) * BK + ((quad ^ (l16 & 3)) * 8));
#pragma unroll
    for (int ni = 0; ni < 2; ++ni)
      bf[ni] = *(const bf16x8*)(Bc + (wn + ni * 16 + l16) * BK + ((quad ^ (l16 & 3)) * 8));
#pragma unroll
    for (int mi = 0; mi < 4; ++mi)
#pragma unroll
      for (int ni = 0; ni < 2; ++ni)
        acc[mi][ni] = __builtin_amdgcn_mfma_f32_16x16x32_bf16(af[mi], bf[ni], acc[mi][ni], 0, 0, 0);
  }
#undef QKV_STAGE

#pragma unroll
  for (int ni = 0; ni < 2; ++ni) {
    const int col = n0 + wn + ni * 16 + l16;
    const float bv = bias[col];
#pragma unroll
    for (int mi = 0; mi < 4; ++mi) {
      const int mrow = m0 + wm + mi * 16 + quad * 4;
      f32x4 a = acc[mi][ni];
      if (!vm) {
#pragma unroll
        for (int r = 0; r < 4; ++r)
          Cout[(size_t)(mrow + r) * N + col] = f2bf(a[r] + bv);
      } else {
        const int bq = mrow >> 11, t = mrow & 2047;
        const int h = col >> 6, d = col & 63;
        ushort4 pk;
        pk.x = f2bf(a[0] + bv); pk.y = f2bf(a[1] + bv);
        pk.z = f2bf(a[2] + bv); pk.w = f2bf(a[3] + bv);
        *(ushort4*)(Cout + ((size_t)((bq * 16 + h) * 64 + d)) * 2048 + t) = pk;
      }
    }
  }
}

// ---------------- Wo GEMM (fp32 out), same 512-thread structure ------------
// 512 blocks grid-cap at 2 blocks/CU -> 16 waves/CU (was 8 with 256 threads).
__global__ __launch_bounds__(512, 4) void gemm_wo(
    const u16* __restrict__ A, const u16* __restrict__ W,
    const float* __restrict__ bias, float* __restrict__ Cout)
{
  constexpr int N = 1024, K = 1024, BK = 32, NT = K / BK;
  __shared__ __align__(16) u16 As[3][128 * BK];
  __shared__ __align__(16) u16 Bs[3][128 * BK];
  const int tid = threadIdx.x;
  const int wave = tid >> 6, lane = tid & 63;
  const int quad = lane >> 4, l16 = lane & 15;
  const int m0 = blockIdx.x * 128, n0 = blockIdx.y * 128;

  const int srow = tid >> 2;
  const int sg = ((tid & 3) ^ (srow & 3)) * 8;
  const u16* ag = A + (size_t)(m0 + srow) * K + sg;
  const u16* bg = W + (size_t)(n0 + srow) * K + sg;

  const int wm = (wave >> 2) * 64, wn = (wave & 3) * 32;
  f32x4 acc[4][2] = {};

#define WO_STAGE(s)                                    \
  do {                                                 \
    gload16(ag, As[s] + wave * 512);                   \
    gload16(bg, Bs[s] + wave * 512);                   \
    ag += BK; bg += BK;                                \
  } while (0)

  WO_STAGE(0);
  WO_STAGE(1);

  int cb = 0, sb = 2;
  for (int kt = 0; kt < NT; ++kt) {
    if (kt + 1 < NT) asm volatile("s_waitcnt vmcnt(2)" ::: "memory");
    else             asm volatile("s_waitcnt vmcnt(0)" ::: "memory");
    __builtin_amdgcn_s_barrier();
    __builtin_amdgcn_sched_barrier(0);
    if (kt + 2 < NT) {
      WO_STAGE(sb);
      sb = (sb == 2) ? 0 : sb + 1;
    }
    const u16* Ac = As[cb];
    const u16* Bc = Bs[cb];
    cb = (cb == 2) ? 0 : cb + 1;
    bf16x8 af[4], bf[2];
#pragma unroll
    for (int mi = 0; mi < 4; ++mi)
      af[mi] = *(const bf16x8*)(Ac + (wm + mi * 16 + l16) * BK + ((quad ^ (l16 & 3)) * 8));
#pragma unroll
    for (int ni = 0; ni < 2; ++ni)
      bf[ni] = *(const bf16x8*)(Bc + (wn + ni * 16 + l16) * BK + ((quad ^ (l16 & 3)) * 8));
#pragma unroll
    for (int mi = 0; mi < 4; ++mi)
#pragma unroll
      for (int ni = 0; ni < 2; ++ni)
        acc[mi][ni] = __builtin_amdgcn_mfma_f32_16x16x32_bf16(af[mi], bf[ni], acc[mi][ni], 0, 0, 0);
  }
#undef WO_STAGE

#pragma unroll
  for (int ni = 0; ni < 2; ++ni) {
    const int col = n0 + wn + ni * 16 + l16;
    const float bv = bias[col];
#pragma unroll
    for (int mi = 0; mi < 4; ++mi) {
      const int mrow = m0 + wm + mi * 16 + quad * 4;
      f32x4 a = acc[mi][ni];
#pragma unroll
      for (int r = 0; r < 4; ++r)
        Cout[(size_t)(mrow + r) * N + col] = a[r] + bv;
    }
  }
}

// ---------------- flash attention (round-5/7 body — measured best 80.2) -----
// KVBLK=128, LDS 81920. Round-8's KVBLK=64 was null-to-negative: occupancy is
// GRID-capped at 2 blocks/CU (512 blocks / 256 CU), so LDS shrink bought
// nothing and doubled barrier count.
__global__ __launch_bounds__(512, 4) void flash_attn(
    const u16* __restrict__ Qp, const u16* __restrict__ Kp,
    const u16* __restrict__ Vt, u16* __restrict__ Ctx)
{
  constexpr int TQ = 2048, DM = 1024, DK = 64;
  __shared__ __align__(16) u16 Ks[2][128 * 64];    // 32768 B
  __shared__ __align__(16) u16 Vts[2][64 * 128];   // 32768 B
  __shared__ __align__(16) u16 Ps[8][16 * 64];     // 16384 B  (total 81920)

  const int bh = blockIdx.x, b = bh >> 4, h = bh & 15;
  const int qt = blockIdx.y;
  const int tid = threadIdx.x, wave = tid >> 6, lane = tid & 63;
  const int quad = lane >> 4, l16 = lane & 15;
  const int q0 = qt * 256 + wave * 32;

  const int C0 = tid, C1 = 512 + tid;
  const int kr0 = C0 >> 3, kr1 = C1 >> 3;
  const u16* kp0 = Kp + (size_t)(b * TQ + kr0) * DM + h * DK + (((C0 & 7) ^ (kr0 & 7)) * 8);
  const u16* kp1 = Kp + (size_t)(b * TQ + kr1) * DM + h * DK + (((C1 & 7) ^ (kr1 & 7)) * 8);
  const int vd0 = C0 >> 4, vd1 = C1 >> 4;
  const u16* vp0 = Vt + (size_t)(bh * DK + vd0) * TQ + (((C0 & 15) ^ (vd0 & 15)) * 8);
  const u16* vp1 = Vt + (size_t)(bh * DK + vd1) * TQ + (((C1 & 15) ^ (vd1 & 15)) * 8);

  bf16x8 qf[2][2];
#pragma unroll
  for (int mi = 0; mi < 2; ++mi)
#pragma unroll
    for (int ks = 0; ks < 2; ++ks)
      qf[mi][ks] = *(const bf16x8*)(Qp + (size_t)(b * TQ + q0 + mi * 16 + l16) * DM
                                       + h * DK + ks * 32 + quad * 8);

  f32x4 O[2][4] = {};
  f32x4 lsum[2] = {};
  const float CS = 0.18033688011112042f;
  const float CB = 0.0028153f;

  bf16x8 onesv;
#pragma unroll
  for (int j = 0; j < 8; ++j) onesv[j] = (short)0x3F80;  // bf16 1.0

  gload16(kp0, &Ks[0][C0 * 8]);
  gload16(kp1, &Ks[0][C1 * 8]);
  gload16(vp0, &Vts[0][C0 * 8]);
  gload16(vp1, &Vts[0][C1 * 8]);
  kp0 += 128 * DM; kp1 += 128 * DM; vp0 += 128; vp1 += 128;
  __syncthreads();

  const int kg = quad ^ (l16 & 7);
  int cur = 0;
  for (int kt = 0; kt < TQ / 128; ++kt) {
    if (kt + 1 < TQ / 128) {
      const int nb = cur ^ 1;
      gload16(kp0, &Ks[nb][C0 * 8]);
      gload16(kp1, &Ks[nb][C1 * 8]);
      gload16(vp0, &Vts[nb][C0 * 8]);
      gload16(vp1, &Vts[nb][C1 * 8]);
      kp0 += 128 * DM; kp1 += 128 * DM; vp0 += 128; vp1 += 128;
    }
    const u16* Kc = Ks[cur];
    const u16* Vc = Vts[cur];
    u16* Psw = Ps[wave];

#pragma unroll
    for (int g = 0; g < 2; ++g) {
      f32x4 Sg[2][4];
      __builtin_amdgcn_s_setprio(1);
#pragma unroll
      for (int cc = 0; cc < 4; ++cc) {
        const int row = (g * 4 + cc) * 16 + l16;
        bf16x8 kf0 = *(const bf16x8*)(Kc + row * 64 + kg * 8);
        bf16x8 kf1 = *(const bf16x8*)(Kc + row * 64 + (kg ^ 4) * 8);
#pragma unroll
        for (int mi = 0; mi < 2; ++mi) {
          f32x4 zz = {};
          zz = __builtin_amdgcn_mfma_f32_16x16x32_bf16(qf[mi][0], kf0, zz, 0, 0, 0);
          Sg[mi][cc] = __builtin_amdgcn_mfma_f32_16x16x32_bf16(qf[mi][1], kf1, zz, 0, 0, 0);
        }
      }
      __builtin_amdgcn_s_setprio(0);
      bf16x8 pf[2][2];
#pragma unroll
      for (int mi = 0; mi < 2; ++mi) {
#pragma unroll
        for (int r = 0; r < 4; ++r) {
          float e0 = __builtin_amdgcn_exp2f(fmaf(Sg[mi][0][r], CS, CB));
          float e1 = __builtin_amdgcn_exp2f(fmaf(Sg[mi][1][r], CS, CB));
          float e2 = __builtin_amdgcn_exp2f(fmaf(Sg[mi][2][r], CS, CB));
          float e3 = __builtin_amdgcn_exp2f(fmaf(Sg[mi][3][r], CS, CB));
          uint2 pk;
          pk.x = packbf2(e0, e1);
          pk.y = packbf2(e2, e3);
          const int pw = quad * 4 + r;
          *(uint2*)(&Psw[pw * 64 + ((l16 * 4) ^ ((pw & 7) << 3))]) = pk;
        }
#pragma unroll
        for (int ksl = 0; ksl < 2; ++ksl)
          pf[mi][ksl] = *(const bf16x8*)(&Psw[l16 * 64 + ((ksl * 32 + quad * 8) ^ ((l16 & 7) << 3))]);
#pragma unroll
        for (int ksl = 0; ksl < 2; ++ksl)
          lsum[mi] = __builtin_amdgcn_mfma_f32_16x16x32_bf16(pf[mi][ksl], onesv, lsum[mi], 0, 0, 0);
      }
      __builtin_amdgcn_s_setprio(1);
#pragma unroll
      for (int ksl = 0; ksl < 2; ++ksl)
#pragma unroll
        for (int ni = 0; ni < 4; ++ni) {
          const int gv = g * 8 + ksl * 4 + quad;
          bf16x8 vf = *(const bf16x8*)(Vc + (ni * 16 + l16) * 128 + ((gv ^ l16) * 8));
          O[0][ni] = __builtin_amdgcn_mfma_f32_16x16x32_bf16(pf[0][ksl], vf, O[0][ni], 0, 0, 0);
          O[1][ni] = __builtin_amdgcn_mfma_f32_16x16x32_bf16(pf[1][ksl], vf, O[1][ni], 0, 0, 0);
        }
      __builtin_amdgcn_s_setprio(0);
    }
    __syncthreads();
    cur ^= 1;
  }

#pragma unroll
  for (int mi = 0; mi < 2; ++mi)
#pragma unroll
    for (int r = 0; r < 4; ++r) {
      const float inv = 1.0f / lsum[mi][r];
      const int q = q0 + mi * 16 + quad * 4 + r;
#pragma unroll
      for (int ni = 0; ni < 4; ++ni) {
        const int col = h * DK + ni * 16 + l16;
        Ctx[(size_t)(b * TQ + q) * DM + col] = f2bf(O[mi][ni][r] * inv);
      }
    }
}

extern "C" void kernel_launch(void* const* d_in, const int* in_sizes, int n_in,
                              void* d_out, int out_size, void* d_ws, size_t ws_size,
                              hipStream_t stream)
{
  (void)in_sizes; (void)n_in; (void)out_size; (void)ws_size;
  const float* query = (const float*)d_in[0];
  const float* key_  = (const float*)d_in[1];
  const float* value = (const float*)d_in[2];
  const float* Wq = (const float*)d_in[3];
  const float* bq = (const float*)d_in[4];
  const float* Wk = (const float*)d_in[5];
  const float* bk = (const float*)d_in[6];
  const float* Wv = (const float*)d_in[7];
  const float* bv = (const float*)d_in[8];
  const float* Wo = (const float*)d_in[9];
  const float* bo = (const float*)d_in[10];

  const size_t MT = (size_t)4 * 2048 * 1024;  // 8M elements
  const size_t WT = (size_t)1024 * 1024;      // 1M elements
  u16* ws  = (u16*)d_ws;
  u16* Xq  = ws;                 // Xq, Xk, Xv contiguous (stride MT)
  u16* Wqb = Xq + 3 * MT;        // Wqb, Wkb, Wvb, Wob contiguous (stride WT)
  u16* Qp  = Wqb + 4 * WT;       // Qp, Kp, Vt contiguous (stride MT)
  u16* Kp  = Qp + MT;
  u16* Vt  = Kp + MT;
  u16* Ctx = Vt + MT;
  u16* Wob = Wqb + 3 * WT;

  cvt_all<<<dim3(8192, 4), 256, 0, stream>>>(
      query, key_, value, Wq, Wk, Wv, Wo, ws);

  gemm_qkv<<<dim3(64, 8, 3), 512, 0, stream>>>(Xq, Wqb, bq, bk, bv, Qp);

  flash_attn<<<dim3(64, 8), 512, 0, stream>>>(Qp, Kp, Vt, Ctx);

  gemm_wo<<<dim3(64, 8), 512, 0, stream>>>(Ctx, Wob, bo, (float*)d_out);
}